// Round 2
// baseline (487.593 us; speedup 1.0000x reference)
//
#include <hip/hip_runtime.h>
#include <math.h>

#define BATCH 64
#define IC 2048
// J = M = N = 16
#define NI 16             // i's per block (serial)
#define NG (IC / NI)      // 128 i-groups
#define NBPB 8            // b's per block (2 per wave)
#define NBG (BATCH / NBPB)// 8 b-groups
// grid = NG * NBG = 1024 blocks -> 4 blocks/CU, 16 waves/CU

// Lane mapping: j = lane&15 (softmax dim, intra-wave bits 0..3),
//               mg = lane>>4 (m-group; lane holds m = 4mg..4mg+3 as float4).
// m-reduction = shfl_xor 16,32 ; softmax-over-j = shfl_xor 1,2,4,8.
// -> zero LDS, zero __syncthreads in the hot kernel.
template <bool FIRST>
__global__ __launch_bounds__(256, 4) void pass_kernel(
    const float* __restrict__ Wt,      // [IC, 16, 16, 16]  (i, j, n, m)
    const float* __restrict__ inp,     // [BATCH, IC, 16]
    const float* __restrict__ vcum,    // [BATCH, 16, 16]   (b, j, m) cumulative v
    float* __restrict__ partial)       // [NG, BATCH, 256]
{
    const int tid  = threadIdx.x;
    const int wave = tid >> 6;
    const int lane = tid & 63;
    const int j    = lane & 15;
    const int mg   = lane >> 4;
    const int g    = blockIdx.x & (NG - 1);
    const int bg   = blockIdx.x >> 7;
    const int i0   = g * NI;
    const int bbase = bg * NBPB + wave * 2;   // this wave's 2 b's

    float4 vc[2];
    if (!FIRST) {
#pragma unroll
        for (int bb = 0; bb < 2; ++bb)
            vc[bb] = *(const float4*)(vcum + (bbase + bb) * 256 + j * 16 + mg * 4);
    }

    float4 acc[2];
    acc[0] = make_float4(0.f, 0.f, 0.f, 0.f);
    acc[1] = make_float4(0.f, 0.f, 0.f, 0.f);

    for (int ii = 0; ii < NI; ++ii) {
        const int i = i0 + ii;
        // W fragment: w[n] = W[i, j, n, 4mg..4mg+3]; 16 x float4 (64 VGPRs),
        // 4 consecutive lanes (same j, mg 0..3) cover 64 contiguous bytes.
        const float4* wp = (const float4*)(Wt + (size_t)i * 4096 + j * 256 + mg * 4);
        float4 w[16];
#pragma unroll
        for (int n = 0; n < 16; ++n) w[n] = wp[n * 4];

#pragma unroll
        for (int bb = 0; bb < 2; ++bb) {
            const int b = bbase + bb;
            const float4* up = (const float4*)(inp + ((size_t)b * IC + i) * 16);
            float4 u0 = up[0], u1 = up[1], u2 = up[2], u3 = up[3];

            float4 h = make_float4(0.f, 0.f, 0.f, 0.f);
#define ACC4(W, S)                                                     \
            h.x = fmaf((W).x, (S), h.x); h.y = fmaf((W).y, (S), h.y);  \
            h.z = fmaf((W).z, (S), h.z); h.w = fmaf((W).w, (S), h.w);
            ACC4(w[0],  u0.x) ACC4(w[1],  u0.y) ACC4(w[2],  u0.z) ACC4(w[3],  u0.w)
            ACC4(w[4],  u1.x) ACC4(w[5],  u1.y) ACC4(w[6],  u1.z) ACC4(w[7],  u1.w)
            ACC4(w[8],  u2.x) ACC4(w[9],  u2.y) ACC4(w[10], u2.z) ACC4(w[11], u2.w)
            ACC4(w[12], u3.x) ACC4(w[13], u3.y) ACC4(w[14], u3.z) ACC4(w[15], u3.w)
#undef ACC4

            if (FIRST) {
                acc[bb].x += h.x; acc[bb].y += h.y;
                acc[bb].z += h.z; acc[bb].w += h.w;
            } else {
                // logit_j = sum_m vc*hat : per-lane dot over 4 m's, then mg-reduce
                float t = h.x * vc[bb].x + h.y * vc[bb].y +
                          h.z * vc[bb].z + h.w * vc[bb].w;
                t += __shfl_xor(t, 16);
                t += __shfl_xor(t, 32);
                // softmax over j (lane bits 0..3); |logit| small -> no max-sub
                const float e = __expf(t);
                float s = e;
                s += __shfl_xor(s, 1);
                s += __shfl_xor(s, 2);
                s += __shfl_xor(s, 4);
                s += __shfl_xor(s, 8);
                const float c = e * __builtin_amdgcn_rcpf(s);
                acc[bb].x = fmaf(c, h.x, acc[bb].x);
                acc[bb].y = fmaf(c, h.y, acc[bb].y);
                acc[bb].z = fmaf(c, h.z, acc[bb].z);
                acc[bb].w = fmaf(c, h.w, acc[bb].w);
            }
        }
    }

#pragma unroll
    for (int bb = 0; bb < 2; ++bb)
        *(float4*)(partial + ((size_t)g * BATCH + (bbase + bb)) * 256 + j * 16 + mg * 4) = acc[bb];
}

// One block per b. Reduce partials over NG groups, squash, update vcum / write out.
__global__ __launch_bounds__(256) void reduce_squash(
    const float* __restrict__ partial, float* __restrict__ vcum,
    float* __restrict__ out, int stage)
{
    const int b = blockIdx.x;
    const int tid = threadIdx.x;   // e = j*16 + m
    const float* p = partial + (size_t)b * 256 + tid;
    float s = 0.0f;
#pragma unroll 4
    for (int gi = 0; gi < NG; ++gi)
        s += p[(size_t)gi * BATCH * 256];
    if (stage == 0) s *= (1.0f / 16.0f);   // uniform c = 1/16 on iteration 0

    float n2 = s * s;
    n2 += __shfl_xor(n2, 1);
    n2 += __shfl_xor(n2, 2);
    n2 += __shfl_xor(n2, 4);
    n2 += __shfl_xor(n2, 8);
    const float scale = n2 / ((1.0f + n2) * sqrtf(n2 + 1e-8f));
    const float v = scale * s;

    const int o = b * 256 + tid;
    if (stage == 0)      vcum[o] = v;
    else if (stage == 1) vcum[o] += v;
    else                 out[o] = v;
}

extern "C" void kernel_launch(void* const* d_in, const int* in_sizes, int n_in,
                              void* d_out, int out_size, void* d_ws, size_t ws_size,
                              hipStream_t stream) {
    const float* inp = (const float*)d_in[0];   // [64, 2048, 16]
    const float* Wt  = (const float*)d_in[1];   // [2048, 16, 16, 16]
    float* out = (float*)d_out;                 // [64, 16, 16]
    float* partial = (float*)d_ws;              // NG*BATCH*256 floats = 8 MB
    float* vcum = partial + (size_t)NG * BATCH * 256;  // 64 KB

    const dim3 gp(NG * NBG), bp(256);

    // iter 0: c uniform -> s0 ; v0 = squash(s0/16); vcum = v0
    pass_kernel<true><<<gp, bp, 0, stream>>>(Wt, inp, nullptr, partial);
    reduce_squash<<<BATCH, 256, 0, stream>>>(partial, vcum, out, 0);
    // iter 1: logits from vcum=v0 -> s1 ; vcum += v1
    pass_kernel<false><<<gp, bp, 0, stream>>>(Wt, inp, vcum, partial);
    reduce_squash<<<BATCH, 256, 0, stream>>>(partial, vcum, out, 1);
    // iter 2: logits from vcum=v0+v1 -> s2 ; out = squash(s2)
    pass_kernel<false><<<gp, bp, 0, stream>>>(Wt, inp, vcum, partial);
    reduce_squash<<<BATCH, 256, 0, stream>>>(partial, vcum, out, 2);
}

// Round 3
// 453.827 us; speedup vs baseline: 1.0744x; 1.0744x over previous
//
#include <hip/hip_runtime.h>
#include <math.h>

#define BATCH 64
#define IC 2048
// J = M = N = 16
#define NIW 8              // i's per wave (serial)
#define NW 4               // waves per block (split i, share b)
#define NIB (NIW * NW)     // 32 i's per block
#define NGB (IC / NIB)     // 64 i-block-groups
#define NB 8               // b's per block (all waves, rolled loop)
#define NBG (BATCH / NB)   // 8 b-groups
// grid = NGB * NBG = 512 blocks, 256 thr -> 2048 waves = 2/SIMD

// Lane mapping: j = lane&15 (softmax dim), mg = lane>>4 (m = 4mg..4mg+3 as float4).
// m-reduce = shfl_xor 16,32 ; softmax-over-j = shfl_xor 1,2,4,8.
template <bool FIRST>
__global__ __launch_bounds__(256, 2) void pass_kernel(
    const float* __restrict__ Wt,      // [IC, 16, 16, 16]  (i, j, n, m)
    const float* __restrict__ inp,     // [BATCH, IC, 16]
    const float* __restrict__ vcum,    // [BATCH, 16, 16]   (b, j, m)
    float* __restrict__ partial)       // [NGB, BATCH, 256]
{
    const int tid  = threadIdx.x;
    const int wave = tid >> 6;
    const int lane = tid & 63;
    const int j    = lane & 15;
    const int mg   = lane >> 4;
    // XCD swizzle: all 8 bg-blocks of one g share blockIdx%8 -> same XCD ->
    // the 8x W re-read is served by that XCD's 4MB L2 (one g-set per XCD).
    const int bi = blockIdx.x;
    const int g  = (bi & 7) | ((bi >> 6) << 3);
    const int bg = (bi >> 3) & 7;
    const int i0 = g * NIB + wave * NIW;
    const int b0 = bg * NB;

    float4 vc[NB];
    if (!FIRST) {
#pragma unroll
        for (int b = 0; b < NB; ++b)
            vc[b] = *(const float4*)(vcum + (b0 + b) * 256 + j * 16 + mg * 4);
    }

    float4 acc[NB];
#pragma unroll
    for (int b = 0; b < NB; ++b) acc[b] = make_float4(0.f, 0.f, 0.f, 0.f);

    for (int ii = 0; ii < NIW; ++ii) {
        const int i = i0 + ii;
        // W fragment: w[n] = W[i, j, n, 4mg..4mg+3]; 16 x float4, hoisted by
        // LICM across the rolled b-loop (keep it ROLLED so loads stay resident).
        const float4* wp = (const float4*)Wt + ((size_t)i * 1024 + j * 64 + mg);
        float4 w[16];
#pragma unroll
        for (int n = 0; n < 16; ++n) w[n] = wp[n * 4];

        const float4* up0 = (const float4*)inp + ((size_t)b0 * IC + i) * 4;
#pragma unroll 2
        for (int b = 0; b < NB; ++b) {
            const float4* up = up0 + (size_t)b * IC * 4;
            float4 u0 = up[0], u1 = up[1], u2 = up[2], u3 = up[3];

            float4 h = make_float4(0.f, 0.f, 0.f, 0.f);
#define ACC4(W, S)                                                     \
            h.x = fmaf((W).x, (S), h.x); h.y = fmaf((W).y, (S), h.y);  \
            h.z = fmaf((W).z, (S), h.z); h.w = fmaf((W).w, (S), h.w);
            ACC4(w[0],  u0.x) ACC4(w[1],  u0.y) ACC4(w[2],  u0.z) ACC4(w[3],  u0.w)
            ACC4(w[4],  u1.x) ACC4(w[5],  u1.y) ACC4(w[6],  u1.z) ACC4(w[7],  u1.w)
            ACC4(w[8],  u2.x) ACC4(w[9],  u2.y) ACC4(w[10], u2.z) ACC4(w[11], u2.w)
            ACC4(w[12], u3.x) ACC4(w[13], u3.y) ACC4(w[14], u3.z) ACC4(w[15], u3.w)
#undef ACC4

            if (FIRST) {
                acc[b].x += h.x; acc[b].y += h.y;
                acc[b].z += h.z; acc[b].w += h.w;
            } else {
                // logit_j = sum_m vcum*hat : 4-m dot per lane, then mg-reduce
                float t = h.x * vc[b].x + h.y * vc[b].y +
                          h.z * vc[b].z + h.w * vc[b].w;
                t += __shfl_xor(t, 16);
                t += __shfl_xor(t, 32);
                // softmax over j (lane bits 0..3); |logit| <= ~10 -> exp safe
                const float e = __expf(t);
                float s = e;
                s += __shfl_xor(s, 1);
                s += __shfl_xor(s, 2);
                s += __shfl_xor(s, 4);
                s += __shfl_xor(s, 8);
                const float c = e * __builtin_amdgcn_rcpf(s);
                acc[b].x = fmaf(c, h.x, acc[b].x);
                acc[b].y = fmaf(c, h.y, acc[b].y);
                acc[b].z = fmaf(c, h.z, acc[b].z);
                acc[b].w = fmaf(c, h.w, acc[b].w);
            }
        }
    }

    // ---- cross-wave (i-direction) reduce via LDS, one barrier per block ----
    __shared__ float red[NW][NB][256];   // 32 KB
#pragma unroll
    for (int b = 0; b < NB; ++b)
        *(float4*)&red[wave][b][j * 16 + mg * 4] = acc[b];
    __syncthreads();
    for (int t = tid; t < NB * 64; t += 256) {   // 2 iterations
        const int b  = t >> 6;
        const int e4 = (t & 63) << 2;
        float4 r0 = *(const float4*)&red[0][b][e4];
        float4 r1 = *(const float4*)&red[1][b][e4];
        float4 r2 = *(const float4*)&red[2][b][e4];
        float4 r3 = *(const float4*)&red[3][b][e4];
        float4 s;
        s.x = (r0.x + r1.x) + (r2.x + r3.x);
        s.y = (r0.y + r1.y) + (r2.y + r3.y);
        s.z = (r0.z + r1.z) + (r2.z + r3.z);
        s.w = (r0.w + r1.w) + (r2.w + r3.w);
        *(float4*)(partial + ((size_t)g * BATCH + (b0 + b)) * 256 + e4) = s;
    }
}

// Grid = BATCH*4 blocks of 64 threads: block (b, quarter-of-j). Reduce over
// NGB groups, squash (m-sum intra-wave: e = j'*16+m, shfl 1,2,4,8), update.
__global__ __launch_bounds__(64) void reduce_squash(
    const float* __restrict__ partial, float* __restrict__ vcum,
    float* __restrict__ out, int stage)
{
    const int b = blockIdx.x >> 2;
    const int q = blockIdx.x & 3;
    const int e = q * 64 + threadIdx.x;
    const float* p = partial + (size_t)b * 256 + e;
    float s = 0.0f;
#pragma unroll 8
    for (int gi = 0; gi < NGB; ++gi)
        s += p[(size_t)gi * BATCH * 256];
    if (stage == 0) s *= (1.0f / 16.0f);   // uniform c = 1/16 on iteration 0

    float n2 = s * s;
    n2 += __shfl_xor(n2, 1);
    n2 += __shfl_xor(n2, 2);
    n2 += __shfl_xor(n2, 4);
    n2 += __shfl_xor(n2, 8);
    const float scale = n2 / ((1.0f + n2) * sqrtf(n2 + 1e-8f));
    const float v = scale * s;

    const int o = b * 256 + e;
    if (stage == 0)      vcum[o] = v;
    else if (stage == 1) vcum[o] += v;
    else                 out[o] = v;
}

extern "C" void kernel_launch(void* const* d_in, const int* in_sizes, int n_in,
                              void* d_out, int out_size, void* d_ws, size_t ws_size,
                              hipStream_t stream) {
    const float* inp = (const float*)d_in[0];   // [64, 2048, 16]
    const float* Wt  = (const float*)d_in[1];   // [2048, 16, 16, 16]
    float* out = (float*)d_out;                 // [64, 16, 16]
    float* partial = (float*)d_ws;              // NGB*BATCH*256 floats = 4 MB
    float* vcum = partial + (size_t)NGB * BATCH * 256;  // 64 KB

    const dim3 gp(NGB * NBG), bp(256);
    const dim3 gr(BATCH * 4), br(64);

    // iter 0: c uniform -> s0 ; v0 = squash(s0/16); vcum = v0
    pass_kernel<true><<<gp, bp, 0, stream>>>(Wt, inp, nullptr, partial);
    reduce_squash<<<gr, br, 0, stream>>>(partial, vcum, out, 0);
    // iter 1: logits from vcum=v0 -> s1 ; vcum += v1
    pass_kernel<false><<<gp, bp, 0, stream>>>(Wt, inp, vcum, partial);
    reduce_squash<<<gr, br, 0, stream>>>(partial, vcum, out, 1);
    // iter 2: logits from vcum=v0+v1 -> s2 ; out = squash(s2)
    pass_kernel<false><<<gp, bp, 0, stream>>>(Wt, inp, vcum, partial);
    reduce_squash<<<gr, br, 0, stream>>>(partial, vcum, out, 2);
}

// Round 4
// 392.577 us; speedup vs baseline: 1.2420x; 1.1560x over previous
//
#include <hip/hip_runtime.h>
#include <math.h>

#define BATCH 64
#define IC 2048
// J = M = N = 16
#define NIW 2               // i's per wave, W resident in VGPRs (128 regs)
#define NW  8               // waves per block (512 threads)
#define NIB (NIW * NW)      // 16 i's per block
#define NGB (IC / NIB)      // 128 i-groups
#define BSPL 2              // b-split: each block does 32 b's
#define NBB (BATCH / BSPL)  // 32
// grid = NGB * BSPL = 256 blocks = 1/CU, 8 waves = 2/SIMD

// Lane map: j = lane&15 (softmax dim), mg = lane>>4 (m = 4mg..4mg+3 as float4).
// m-reduce = shfl_xor 16,32 ; softmax-over-j = shfl_xor 1,2,4,8.
// b OUTER loop: per-b state is scalar float4s (no arrays -> no scratch),
// W fragments are constant-indexed -> must be register-resident.
template <bool FIRST>
__global__ __launch_bounds__(512, 2) void pass_kernel(
    const float* __restrict__ Wt,      // [IC, 16, 16, 16]  (i, j, n, m)
    const float* __restrict__ inp,     // [BATCH, IC, 16]
    const float* __restrict__ vcum,    // [BATCH, 16, 16]   (b, j, m)
    float* __restrict__ partial)       // [NGB, BATCH, 256]
{
    const int tid  = threadIdx.x;
    const int wave = tid >> 6;
    const int lane = tid & 63;
    const int j    = lane & 15;
    const int mg   = lane >> 4;
    const int bi   = blockIdx.x;
    const int g    = (bi & 7) | ((bi >> 4) << 3);   // twins bi, bi+8 -> same XCD
    const int half = (bi >> 3) & 1;
    const int b0   = half * NBB;
    const int ibase = g * NIB + wave * NIW;

    // block-shared accumulator, lane-contiguous layout: [bloc][lane + 64*c]
    __shared__ float lacc[NBB * 256];   // 32 KB
    for (int t = tid; t < NBB * 64; t += 512)
        *(float4*)&lacc[t * 4] = make_float4(0.f, 0.f, 0.f, 0.f);

    // resident W fragments: w[n] = W[i, j, n, 4mg..4mg+3]
    const float4* wp = (const float4*)Wt + ((size_t)ibase * 1024 + j * 64 + mg);
    float4 w0[16], w1[16];
#pragma unroll
    for (int n = 0; n < 16; ++n) { w0[n] = wp[n * 4]; w1[n] = wp[1024 + n * 4]; }

    __syncthreads();   // lacc zeros visible

    const int bst = (wave * 4) & (NBB - 1);   // stagger waves across b
    int bloc = bst;
    // prefetch b-iteration 0: u covers both i's (128 B contiguous)
    const float4* up = (const float4*)(inp + ((size_t)(b0 + bloc) * IC + ibase) * 16);
    float4 u[8];
#pragma unroll
    for (int q = 0; q < 8; ++q) u[q] = up[q];
    float4 vcn;
    if (!FIRST)
        vcn = *(const float4*)(vcum + (b0 + bloc) * 256 + j * 16 + mg * 4);

    for (int bb = 0; bb < NBB; ++bb) {
        const int cb = bloc;
        float4 uc[8];
#pragma unroll
        for (int q = 0; q < 8; ++q) uc[q] = u[q];
        const float4 vcc = vcn;
        // issue next-b loads before compute (SW pipeline)
        bloc = (bst + bb + 1) & (NBB - 1);
        if (bb + 1 < NBB) {
            const float4* upn = (const float4*)(inp + ((size_t)(b0 + bloc) * IC + ibase) * 16);
#pragma unroll
            for (int q = 0; q < 8; ++q) u[q] = upn[q];
            if (!FIRST)
                vcn = *(const float4*)(vcum + (b0 + bloc) * 256 + j * 16 + mg * 4);
        }

        float4 h0 = make_float4(0.f, 0.f, 0.f, 0.f);
        float4 h1 = make_float4(0.f, 0.f, 0.f, 0.f);
#define ACC4(H, W, S)                                                   \
        (H).x = fmaf((W).x, (S), (H).x); (H).y = fmaf((W).y, (S), (H).y); \
        (H).z = fmaf((W).z, (S), (H).z); (H).w = fmaf((W).w, (S), (H).w);
        ACC4(h0, w0[0],  uc[0].x) ACC4(h0, w0[1],  uc[0].y)
        ACC4(h0, w0[2],  uc[0].z) ACC4(h0, w0[3],  uc[0].w)
        ACC4(h0, w0[4],  uc[1].x) ACC4(h0, w0[5],  uc[1].y)
        ACC4(h0, w0[6],  uc[1].z) ACC4(h0, w0[7],  uc[1].w)
        ACC4(h0, w0[8],  uc[2].x) ACC4(h0, w0[9],  uc[2].y)
        ACC4(h0, w0[10], uc[2].z) ACC4(h0, w0[11], uc[2].w)
        ACC4(h0, w0[12], uc[3].x) ACC4(h0, w0[13], uc[3].y)
        ACC4(h0, w0[14], uc[3].z) ACC4(h0, w0[15], uc[3].w)
        ACC4(h1, w1[0],  uc[4].x) ACC4(h1, w1[1],  uc[4].y)
        ACC4(h1, w1[2],  uc[4].z) ACC4(h1, w1[3],  uc[4].w)
        ACC4(h1, w1[4],  uc[5].x) ACC4(h1, w1[5],  uc[5].y)
        ACC4(h1, w1[6],  uc[5].z) ACC4(h1, w1[7],  uc[5].w)
        ACC4(h1, w1[8],  uc[6].x) ACC4(h1, w1[9],  uc[6].y)
        ACC4(h1, w1[10], uc[6].z) ACC4(h1, w1[11], uc[6].w)
        ACC4(h1, w1[12], uc[7].x) ACC4(h1, w1[13], uc[7].y)
        ACC4(h1, w1[14], uc[7].z) ACC4(h1, w1[15], uc[7].w)
#undef ACC4

        float4 a;
        if (FIRST) {
            a.x = h0.x + h1.x; a.y = h0.y + h1.y;
            a.z = h0.z + h1.z; a.w = h0.w + h1.w;
        } else {
            // logits for both i's (independent routing chains, ILP-friendly)
            float t0 = h0.x * vcc.x + h0.y * vcc.y + h0.z * vcc.z + h0.w * vcc.w;
            float t1 = h1.x * vcc.x + h1.y * vcc.y + h1.z * vcc.z + h1.w * vcc.w;
            t0 += __shfl_xor(t0, 16); t1 += __shfl_xor(t1, 16);
            t0 += __shfl_xor(t0, 32); t1 += __shfl_xor(t1, 32);
            const float e0 = __expf(t0), e1 = __expf(t1);
            float s0 = e0, s1 = e1;
            s0 += __shfl_xor(s0, 1); s1 += __shfl_xor(s1, 1);
            s0 += __shfl_xor(s0, 2); s1 += __shfl_xor(s1, 2);
            s0 += __shfl_xor(s0, 4); s1 += __shfl_xor(s1, 4);
            s0 += __shfl_xor(s0, 8); s1 += __shfl_xor(s1, 8);
            const float c0 = e0 * __builtin_amdgcn_rcpf(s0);
            const float c1 = e1 * __builtin_amdgcn_rcpf(s1);
            a.x = fmaf(c0, h0.x, c1 * h1.x);
            a.y = fmaf(c0, h0.y, c1 * h1.y);
            a.z = fmaf(c0, h0.z, c1 * h1.z);
            a.w = fmaf(c0, h0.w, c1 * h1.w);
        }
        // conflict-free (2-way) LDS atomic accumulate: addr = lane + 64*c
        float* lp = &lacc[cb * 256 + lane];
        atomicAdd(lp,       a.x);
        atomicAdd(lp + 64,  a.y);
        atomicAdd(lp + 128, a.z);
        atomicAdd(lp + 192, a.w);
    }
    __syncthreads();

    // write partial in standard [b][j*16+m] layout, coalesced float4 stores.
    // stored el(e): e=4q+c -> lds addr = ob*256 + (q&3)*16 + (q>>2) + 64*c
#pragma unroll
    for (int r = 0; r < (NBB * 64) / 512; ++r) {   // 4 iters
        const int idx = r * 512 + tid;
        const int ob  = idx >> 6;
        const int q   = idx & 63;
        const int base = ob * 256 + ((q & 3) << 4) + (q >> 2);
        float4 v;
        v.x = lacc[base];
        v.y = lacc[base + 64];
        v.z = lacc[base + 128];
        v.w = lacc[base + 192];
        *(float4*)(partial + ((size_t)g * BATCH + b0 + ob) * 256 + q * 4) = v;
    }
}

// Grid = BATCH*4 blocks of 64 threads. Reduce over NGB groups, squash
// (m-sum intra-wave: e = j*16+m, shfl 1,2,4,8), update vcum / write out.
__global__ __launch_bounds__(64) void reduce_squash(
    const float* __restrict__ partial, float* __restrict__ vcum,
    float* __restrict__ out, int stage)
{
    const int b = blockIdx.x >> 2;
    const int q = blockIdx.x & 3;
    const int e = q * 64 + threadIdx.x;
    const float* p = partial + (size_t)b * 256 + e;
    float s = 0.0f;
#pragma unroll 8
    for (int gi = 0; gi < NGB; ++gi)
        s += p[(size_t)gi * BATCH * 256];
    if (stage == 0) s *= (1.0f / 16.0f);   // uniform c = 1/16 on iteration 0

    float n2 = s * s;
    n2 += __shfl_xor(n2, 1);
    n2 += __shfl_xor(n2, 2);
    n2 += __shfl_xor(n2, 4);
    n2 += __shfl_xor(n2, 8);
    const float scale = n2 / ((1.0f + n2) * sqrtf(n2 + 1e-8f));
    const float v = scale * s;

    const int o = b * 256 + e;
    if (stage == 0)      vcum[o] = v;
    else if (stage == 1) vcum[o] += v;
    else                 out[o] = v;
}

extern "C" void kernel_launch(void* const* d_in, const int* in_sizes, int n_in,
                              void* d_out, int out_size, void* d_ws, size_t ws_size,
                              hipStream_t stream) {
    const float* inp = (const float*)d_in[0];   // [64, 2048, 16]
    const float* Wt  = (const float*)d_in[1];   // [2048, 16, 16, 16]
    float* out = (float*)d_out;                 // [64, 16, 16]
    float* partial = (float*)d_ws;              // NGB*BATCH*256 floats = 8.4 MB
    float* vcum = partial + (size_t)NGB * BATCH * 256;  // 64 KB

    const dim3 gp(NGB * BSPL), bp(512);
    const dim3 gr(BATCH * 4), br(64);

    // iter 0: c uniform -> s0 ; v0 = squash(s0/16); vcum = v0
    pass_kernel<true><<<gp, bp, 0, stream>>>(Wt, inp, nullptr, partial);
    reduce_squash<<<gr, br, 0, stream>>>(partial, vcum, out, 0);
    // iter 1: logits from vcum=v0 -> s1 ; vcum += v1
    pass_kernel<false><<<gp, bp, 0, stream>>>(Wt, inp, vcum, partial);
    reduce_squash<<<gr, br, 0, stream>>>(partial, vcum, out, 1);
    // iter 2: logits from vcum=v0+v1 -> s2 ; out = squash(s2)
    pass_kernel<false><<<gp, bp, 0, stream>>>(Wt, inp, vcum, partial);
    reduce_squash<<<gr, br, 0, stream>>>(partial, vcum, out, 2);
}